// Round 1
// baseline (50.808 us; speedup 1.0000x reference)
//
#include <hip/hip_runtime.h>

#define N_MEM 8
#define BSZ   64
#define DK    256
#define DV    256

// One block per (n, b) pair: processes the 256x256 f32 state matrix.
// new_state[k][v] = lam * state[k][v] + (rho*alpha) * key[k] * value[v]
// readout[v]     += query[k] * new_state[k][v]
__global__ __launch_bounds__(1024) void mom_kernel(
    const float* __restrict__ states,   // [N, B, DK, DV]
    const float* __restrict__ key,      // [B, DK]
    const float* __restrict__ value,    // [B, DV]
    const float* __restrict__ alpha,    // [B, 1]
    const float* __restrict__ rho,      // [B, N]
    const float* __restrict__ lam,      // [B, N]
    const float* __restrict__ query,    // [B, DK]
    float* __restrict__ out_states,     // [N, B, DK, DV]
    float* __restrict__ out_read)       // [N, B, DV]
{
    const int bid = blockIdx.x;          // n*B + b
    const int n   = bid >> 6;            // bid / 64
    const int b   = bid & 63;            // bid % 64
    const int t   = threadIdx.x;

    __shared__ float  s_key[DK];
    __shared__ float  s_q[DK];
    __shared__ float4 s_val4[DV / 4];
    __shared__ float4 s_red[1024];

    // Stage the per-b rows into LDS (once per block).
    if (t < DK) {
        s_key[t] = key[b * DK + t];
        s_q[t]   = query[b * DK + t];
    } else if (t < DK + DV / 4) {
        const int v4 = t - DK;
        s_val4[v4] = reinterpret_cast<const float4*>(value + (size_t)b * DV)[v4];
    }
    const float lam_s = lam[b * N_MEM + n];
    const float w_s   = rho[b * N_MEM + n] * alpha[b];
    __syncthreads();

    const size_t base = (size_t)bid * (DK * DV);
    const float4* __restrict__ sp = reinterpret_cast<const float4*>(states + base);
    float4*       __restrict__ op = reinterpret_cast<float4*>(out_states + base);

    // Each thread owns a fixed v-column (4 floats) because 1024 % 64 == 0:
    //   flat float4 index idx = t + it*1024  ->  v4 = idx & 63 = t & 63 (const),
    //   k = idx >> 6 = (t >> 6) + it*16.
    const int    v4  = t & 63;
    const float4 val = s_val4[v4];
    float4 racc = make_float4(0.f, 0.f, 0.f, 0.f);

#pragma unroll
    for (int it = 0; it < 16; ++it) {
        const int idx = t + it * 1024;
        const int k   = idx >> 6;           // wave-uniform: LDS broadcast
        const float4 s = sp[idx];
        const float  kw = w_s * s_key[k];
        float4 ns;
        ns.x = lam_s * s.x + kw * val.x;
        ns.y = lam_s * s.y + kw * val.y;
        ns.z = lam_s * s.z + kw * val.z;
        ns.w = lam_s * s.w + kw * val.w;
        op[idx] = ns;
        const float q = s_q[k];
        racc.x += q * ns.x;
        racc.y += q * ns.y;
        racc.z += q * ns.z;
        racc.w += q * ns.w;
    }

    // Reduce readout across the 16 threads sharing each v-column.
    s_red[t] = racc;
    __syncthreads();
    if (t < 64) {
        float4 acc = s_red[t];
#pragma unroll
        for (int g = 1; g < 16; ++g) {
            const float4 o = s_red[t + g * 64];
            acc.x += o.x;
            acc.y += o.y;
            acc.z += o.z;
            acc.w += o.w;
        }
        reinterpret_cast<float4*>(out_read + (size_t)bid * DV)[t] = acc;
    }
}

extern "C" void kernel_launch(void* const* d_in, const int* in_sizes, int n_in,
                              void* d_out, int out_size, void* d_ws, size_t ws_size,
                              hipStream_t stream) {
    const float* states = (const float*)d_in[0];
    const float* key    = (const float*)d_in[1];
    const float* value  = (const float*)d_in[2];
    const float* alpha  = (const float*)d_in[3];
    const float* rho    = (const float*)d_in[4];
    const float* lam    = (const float*)d_in[5];
    const float* query  = (const float*)d_in[6];

    float* out_states = (float*)d_out;                               // N*B*DK*DV
    float* out_read   = out_states + (size_t)N_MEM * BSZ * DK * DV;  // N*B*DV

    dim3 grid(N_MEM * BSZ);
    dim3 block(1024);
    mom_kernel<<<grid, block, 0, stream>>>(states, key, value, alpha, rho, lam,
                                           query, out_states, out_read);
}